// Round 4
// baseline (126.610 us; speedup 1.0000x reference)
//
#include <hip/hip_runtime.h>
#include <hip/hip_bf16.h>

#define B_   64
#define H_   1024
#define E_   512
#define V_   50000
#define S_   400
#define EXTV 50100        // V + 100
#define K2   2048         // 2H
#define KP   2560         // 2H + E
#define VP   50016        // padded e row stride (multiple of 16)
#define NBLK 782          // ceil(V / 64)
#define PSTR 800          // padded partial-sum stride
#define KCH  16           // split-K chunks for mid GEMM

typedef float  f32x4  __attribute__((ext_vector_type(4)));
typedef __bf16 bf16x8 __attribute__((ext_vector_type(8)));

// asm global load: 16B into dst, base VGPR-pair + literal byte offset.
#define GLD(dst, base, imm)                                                     \
    asm volatile("global_load_dwordx4 %0, %1, off offset:%2"                    \
                 : "=v"(dst) : "v"(base), "n"(imm) : "memory")

static __device__ __forceinline__ bf16x8 pack_bf16(f32x4 a, f32x4 b) {
    bf16x8 r;
    r[0] = (__bf16)a[0]; r[1] = (__bf16)a[1]; r[2] = (__bf16)a[2]; r[3] = (__bf16)a[3];
    r[4] = (__bf16)b[0]; r[5] = (__bf16)b[1]; r[6] = (__bf16)b[2]; r[7] = (__bf16)b[3];
    return r;
}

// ---------------- p_gen: 64 dots of length 2560 -----------------------------
__global__ __launch_bounds__(256) void k_pgen(const float* __restrict__ dec,
                                              const float* __restrict__ ctx,
                                              const float* __restrict__ emb,
                                              const float* __restrict__ Wp,
                                              const float* __restrict__ bp,
                                              float* __restrict__ pg,
                                              float* __restrict__ out1) {
    int b = blockIdx.x;
    int tid = threadIdx.x;
    float s = 0.f;
    for (int k = tid; k < KP; k += 256) {
        float x;
        if (k < H_)          x = dec[b * H_ + k];
        else if (k < 2 * H_) x = ctx[b * H_ + k - H_];
        else                 x = emb[b * E_ + k - 2 * H_];
        s += x * Wp[k];
    }
#pragma unroll
    for (int m = 32; m >= 1; m >>= 1) s += __shfl_xor(s, m);
    __shared__ float r[4];
    int wave = tid >> 6, lane = tid & 63;
    if (lane == 0) r[wave] = s;
    __syncthreads();
    if (tid == 0) {
        float t = r[0] + r[1] + r[2] + r[3] + bp[0];
        float p = 1.f / (1.f + __expf(-t));
        pg[b]   = p;
        out1[b] = p;
    }
}

// ---------------- mid GEMM (split-K 16): M=64, N=1024, K=2048 ---------------
__global__ __launch_bounds__(256, 4) void k_gemm_mid(const float* __restrict__ dec,
                                                     const float* __restrict__ ctx,
                                                     const float* __restrict__ Wm,
                                                     float* __restrict__ pmid) {
    int nt   = blockIdx.x;             // 0..15  (h-tile of 64)
    int kc   = blockIdx.y;             // 0..15  (K-chunk of 128)
    int wave = threadIdx.x >> 6;
    int lane = threadIdx.x & 63;
    int lr   = lane & 15, lg = lane >> 4;
    int col  = nt * 64 + wave * 16 + lr;          // h index
    const float* xb   = (kc < 8) ? dec : ctx;
    int kbase         = (kc & 7) * 128;
    const float* wrow = Wm + (size_t)col * K2 + kc * 128 + lg * 8;
    const float* xrow = xb + (size_t)lr * H_ + kbase + lg * 8;

    f32x4 w0s[4], w1s[4];
#pragma unroll
    for (int p = 0; p < 4; ++p) {
        w0s[p] = *(const f32x4*)(wrow + p * 32);
        w1s[p] = *(const f32x4*)(wrow + p * 32 + 4);
    }
    f32x4 acc[4] = {};
#pragma unroll
    for (int i = 0; i < 4; ++i) {
        f32x4 a0[4], a1[4];
#pragma unroll
        for (int mf = 0; mf < 4; ++mf) {
            const float* xp = xrow + (size_t)(mf * 16) * H_ + i * 32;
            a0[mf] = *(const f32x4*)xp;
            a1[mf] = *(const f32x4*)(xp + 4);
        }
        bf16x8 bf = pack_bf16(w0s[i], w1s[i]);
#pragma unroll
        for (int mf = 0; mf < 4; ++mf) {
            bf16x8 af = pack_bf16(a0[mf], a1[mf]);
            acc[mf] = __builtin_amdgcn_mfma_f32_16x16x32_bf16(af, bf, acc[mf], 0, 0, 0);
        }
    }
#pragma unroll
    for (int mf = 0; mf < 4; ++mf)
#pragma unroll
        for (int r = 0; r < 4; ++r) {
            int row = mf * 16 + lg * 4 + r;       // batch index
            pmid[((size_t)kc * B_ + row) * H_ + col] = acc[mf][r];
        }
}

// ---------------- reduce split-K partials, bias, tanh, -> bf16 --------------
__global__ __launch_bounds__(256) void k_mid_reduce(const float* __restrict__ pmid,
                                                    const float* __restrict__ bm,
                                                    __bf16* __restrict__ midb) {
    int idx = blockIdx.x * 256 + threadIdx.x;     // 65536
    int h = idx & (H_ - 1);
    int m = idx >> 10;
    float s = bm[h];
#pragma unroll
    for (int kc = 0; kc < KCH; ++kc) s += pmid[((size_t)kc * B_ + m) * H_ + h];
    midb[idx] = (__bf16)tanhf(s);
}

// ---------------- big GEMM: e = exp(clip(mid @ Wv^T + bv) - 50) -------------
// No LDS, no barriers: per-wave asm-load pipeline.
// W (HBM): depth-4 rotating slots, prefetch distance 3 iters.
// A (midb, L1/L2-resident): depth-2, prefetch distance 1 iter.
// Per iter issue A[i+1](4 loads) then W[i+3](2 loads); wait vmcnt(8) retires
// exactly through A[i] (W[i] is older). Tail N: i=29->6, 30->4, 31->0.
__global__ __launch_bounds__(256, 4) void k_gemm_vocab(const __bf16* __restrict__ midb,
                                                       const float* __restrict__ Wv,
                                                       const float* __restrict__ bv,
                                                       float* __restrict__ e,
                                                       float* __restrict__ psum) {
    int tid  = threadIdx.x;
    int wave = tid >> 6;
    int lane = tid & 63;
    int lr   = lane & 15, lg = lane >> 4;
    int blk  = blockIdx.x;
    int col  = blk * 64 + wave * 16 + lr;          // global vocab col
    bool valid = col < V_;
    int colc = valid ? col : V_ - 1;

    const char* baseW  = (const char*)(Wv + (size_t)colc * H_ + lg * 8);
    const char* baseA0 = (const char*)(midb + (size_t)(0 * 16 + lr) * H_ + lg * 8);
    const char* baseA1 = (const char*)(midb + (size_t)(1 * 16 + lr) * H_ + lg * 8);
    const char* baseA2 = (const char*)(midb + (size_t)(2 * 16 + lr) * H_ + lg * 8);
    const char* baseA3 = (const char*)(midb + (size_t)(3 * 16 + lr) * H_ + lg * 8);

    f32x4  w0s[4], w1s[4];          // W slots (literal-indexed only)
    bf16x8 as_[2][4];               // A slots
    f32x4  acc[4] = {};

    // ---- prologue: W[0..2], then A[0] (A last so vmcnt(6) at iter0 works) --
    GLD(w0s[0], baseW, 0);    GLD(w1s[0], baseW, 16);
    GLD(w0s[1], baseW, 128);  GLD(w1s[1], baseW, 144);
    GLD(w0s[2], baseW, 256);  GLD(w1s[2], baseW, 272);
    GLD(as_[0][0], baseA0, 0); GLD(as_[0][1], baseA1, 0);
    GLD(as_[0][2], baseA2, 0); GLD(as_[0][3], baseA3, 0);

#define VBODY(i, N, DOA, DOW) do {                                              \
        if (DOA) {                                                              \
            GLD(as_[((i)+1)&1][0], baseA0, ((i)+1)*64);                         \
            GLD(as_[((i)+1)&1][1], baseA1, ((i)+1)*64);                         \
            GLD(as_[((i)+1)&1][2], baseA2, ((i)+1)*64);                         \
            GLD(as_[((i)+1)&1][3], baseA3, ((i)+1)*64);                         \
        }                                                                       \
        if (DOW) {                                                              \
            GLD(w0s[((i)+3)&3], baseW, ((i)+3)*128);                            \
            GLD(w1s[((i)+3)&3], baseW, ((i)+3)*128 + 16);                       \
        }                                                                       \
        asm volatile("s_waitcnt vmcnt(%0)" :: "n"(N) : "memory");               \
        __builtin_amdgcn_sched_barrier(0);                                      \
        bf16x8 bfr = pack_bf16(w0s[(i)&3], w1s[(i)&3]);                         \
        acc[0] = __builtin_amdgcn_mfma_f32_16x16x32_bf16(as_[(i)&1][0], bfr, acc[0], 0, 0, 0); \
        acc[1] = __builtin_amdgcn_mfma_f32_16x16x32_bf16(as_[(i)&1][1], bfr, acc[1], 0, 0, 0); \
        acc[2] = __builtin_amdgcn_mfma_f32_16x16x32_bf16(as_[(i)&1][2], bfr, acc[2], 0, 0, 0); \
        acc[3] = __builtin_amdgcn_mfma_f32_16x16x32_bf16(as_[(i)&1][3], bfr, acc[3], 0, 0, 0); \
    } while (0)

    VBODY(0, 6, 1, 1);
    VBODY(1, 8, 1, 1);  VBODY(2, 8, 1, 1);  VBODY(3, 8, 1, 1);  VBODY(4, 8, 1, 1);
    VBODY(5, 8, 1, 1);  VBODY(6, 8, 1, 1);  VBODY(7, 8, 1, 1);  VBODY(8, 8, 1, 1);
    VBODY(9, 8, 1, 1);  VBODY(10, 8, 1, 1); VBODY(11, 8, 1, 1); VBODY(12, 8, 1, 1);
    VBODY(13, 8, 1, 1); VBODY(14, 8, 1, 1); VBODY(15, 8, 1, 1); VBODY(16, 8, 1, 1);
    VBODY(17, 8, 1, 1); VBODY(18, 8, 1, 1); VBODY(19, 8, 1, 1); VBODY(20, 8, 1, 1);
    VBODY(21, 8, 1, 1); VBODY(22, 8, 1, 1); VBODY(23, 8, 1, 1); VBODY(24, 8, 1, 1);
    VBODY(25, 8, 1, 1); VBODY(26, 8, 1, 1); VBODY(27, 8, 1, 1); VBODY(28, 8, 1, 1);
    VBODY(29, 6, 1, 0); VBODY(30, 4, 1, 0); VBODY(31, 0, 0, 0);
#undef VBODY

    float bias = valid ? bv[col] : 0.f;
    __shared__ float wsum[4][64];
#pragma unroll
    for (int mf = 0; mf < 4; ++mf) {
#pragma unroll
        for (int r = 0; r < 4; ++r) {
            int row = mf * 16 + lg * 4 + r;       // batch index
            float logit = acc[mf][r] + bias;
            logit = fminf(fmaxf(logit, -50.f), 50.f);
            float ev = valid ? __expf(logit - 50.f) : 0.f;
            if (valid) e[(size_t)row * VP + col] = ev;
            float s = ev;
            s += __shfl_xor(s, 1); s += __shfl_xor(s, 2);
            s += __shfl_xor(s, 4); s += __shfl_xor(s, 8);
            if (lr == 0) wsum[wave][row] = s;
        }
    }
    __syncthreads();
    if (threadIdx.x < 64) {
        int row = threadIdx.x;
        float t = wsum[0][row] + wsum[1][row] + wsum[2][row] + wsum[3][row];
        psum[(size_t)row * PSTR + blk] = t;
    }
}

// ---------------- Z reduction: zinv[b] = 1 / sum_blk psum ------------------
__global__ __launch_bounds__(256) void k_zred(const float* __restrict__ psum,
                                              float* __restrict__ zinv) {
    int b = blockIdx.x;
    int tid = threadIdx.x;
    float s = 0.f;
    for (int i = tid; i < NBLK; i += 256) s += psum[(size_t)b * PSTR + i];
#pragma unroll
    for (int m = 32; m >= 1; m >>= 1) s += __shfl_xor(s, m);
    __shared__ float r[4];
    int wave = tid >> 6, lane = tid & 63;
    if (lane == 0) r[wave] = s;
    __syncthreads();
    if (tid == 0) zinv[b] = 1.f / (r[0] + r[1] + r[2] + r[3]);
}

// ---------------- vocab_dist + generation part of final_dist ---------------
__global__ __launch_bounds__(256) void k_final(const float* __restrict__ e,
                                               const float* __restrict__ zinv,
                                               const float* __restrict__ pg,
                                               float* __restrict__ out0,
                                               float* __restrict__ out2) {
    int idx = blockIdx.x * 256 + threadIdx.x;     // < 64*50100
    if (idx >= B_ * EXTV) return;
    int b = idx / EXTV;
    int v = idx - b * EXTV;
    float o = 0.f;
    if (v < V_) {
        float vd = e[(size_t)b * VP + v] * zinv[b];
        out2[(size_t)b * V_ + v] = vd;
        o = pg[b] * vd;
    }
    out0[idx] = o;
}

// ---------------- copy-distribution scatter --------------------------------
__global__ __launch_bounds__(256) void k_scatter(const float* __restrict__ attn,
                                                 const int* __restrict__ sid,
                                                 const int* __restrict__ oov,
                                                 const float* __restrict__ pg,
                                                 float* __restrict__ out0) {
    int idx = blockIdx.x * 256 + threadIdx.x;
    if (idx >= B_ * S_) return;
    int b = idx / S_;
    int m = oov[idx];
    int tgt = (m >= 0) ? (V_ + m) : sid[idx];
    float w = (1.f - pg[b]) * attn[idx];
    atomicAdd(out0 + (size_t)b * EXTV + tgt, w);
}

extern "C" void kernel_launch(void* const* d_in, const int* in_sizes, int n_in,
                              void* d_out, int out_size, void* d_ws, size_t ws_size,
                              hipStream_t stream) {
    const float* dec  = (const float*)d_in[0];
    const float* ctx  = (const float*)d_in[1];
    const float* emb  = (const float*)d_in[2];
    const float* attn = (const float*)d_in[3];
    const int*   sid  = (const int*)d_in[4];
    const int*   oov  = (const int*)d_in[5];
    // d_in[6] = vocab_size (known statically = 50000)
    const float* Wm   = (const float*)d_in[7];
    const float* bm   = (const float*)d_in[8];
    const float* Wp   = (const float*)d_in[9];
    const float* bp   = (const float*)d_in[10];
    const float* Wv   = (const float*)d_in[11];
    const float* bv   = (const float*)d_in[12];

    float* out0 = (float*)d_out;                  // final_dist [64][50100]
    float* out1 = out0 + (size_t)B_ * EXTV;       // p_gen      [64]
    float* out2 = out1 + B_;                      // vocab_dist [64][50000]

    float*  e    = (float*)d_ws;                  // [64][VP]
    float*  psum = e + (size_t)B_ * VP;           // [64][PSTR]
    float*  zinv = psum + (size_t)B_ * PSTR;      // [64]
    float*  pg   = zinv + 64;                     // [64]
    float*  pmid = pg + 64;                       // [KCH][64][1024]
    __bf16* midb = (__bf16*)(pmid + (size_t)KCH * B_ * H_); // [64][1024]

    k_pgen<<<B_, 256, 0, stream>>>(dec, ctx, emb, Wp, bp, pg, out1);
    dim3 gmid(16, KCH);
    k_gemm_mid<<<gmid, 256, 0, stream>>>(dec, ctx, Wm, pmid);
    k_mid_reduce<<<(B_ * H_) / 256, 256, 0, stream>>>(pmid, bm, midb);
    k_gemm_vocab<<<NBLK, 256, 0, stream>>>((const __bf16*)midb, Wv, bv, e, psum);
    k_zred<<<B_, 256, 0, stream>>>(psum, zinv);
    k_final<<<(B_ * EXTV + 255) / 256, 256, 0, stream>>>(e, zinv, pg, out0, out2);
    k_scatter<<<(B_ * S_ + 255) / 256, 256, 0, stream>>>(attn, sid, oov, pg, out0);
}

// Round 6
// 110.712 us; speedup vs baseline: 1.1436x; 1.1436x over previous
//
#include <hip/hip_runtime.h>
#include <hip/hip_bf16.h>

#define B_   64
#define H_   1024
#define E_   512
#define V_   50000
#define S_   400
#define EXTV 50100        // V + 100
#define K2   2048         // 2H
#define KP   2560         // 2H + E
#define VP   50016        // padded e row stride (multiple of 16)
#define NBLK 782          // ceil(V / 64)
#define PSTR 3200         // psum stride: NBLK*4 waves, padded
#define NB4  3128         // NBLK*4
#define KCH  16           // split-K chunks for mid GEMM

typedef float  f32x4  __attribute__((ext_vector_type(4)));
typedef __bf16 bf16x8 __attribute__((ext_vector_type(8)));

typedef __attribute__((address_space(1))) const void gas_t;
typedef __attribute__((address_space(3))) void las_t;

// asm global load: 16B into dst, base VGPR-pair + literal byte offset.
#define GLD(dst, base, imm)                                                     \
    asm volatile("global_load_dwordx4 %0, %1, off offset:%2"                    \
                 : "=v"(dst) : "v"(base), "n"(imm) : "memory")

static __device__ __forceinline__ bf16x8 pack_bf16(f32x4 a, f32x4 b) {
    bf16x8 r;
    r[0] = (__bf16)a[0]; r[1] = (__bf16)a[1]; r[2] = (__bf16)a[2]; r[3] = (__bf16)a[3];
    r[4] = (__bf16)b[0]; r[5] = (__bf16)b[1]; r[6] = (__bf16)b[2]; r[7] = (__bf16)b[3];
    return r;
}

// ---------------- p_gen: 64 dots of length 2560 -----------------------------
__global__ __launch_bounds__(256) void k_pgen(const float* __restrict__ dec,
                                              const float* __restrict__ ctx,
                                              const float* __restrict__ emb,
                                              const float* __restrict__ Wp,
                                              const float* __restrict__ bp,
                                              float* __restrict__ pg,
                                              float* __restrict__ out1) {
    int b = blockIdx.x;
    int tid = threadIdx.x;
    float s = 0.f;
    for (int k = tid; k < KP; k += 256) {
        float x;
        if (k < H_)          x = dec[b * H_ + k];
        else if (k < 2 * H_) x = ctx[b * H_ + k - H_];
        else                 x = emb[b * E_ + k - 2 * H_];
        s += x * Wp[k];
    }
#pragma unroll
    for (int m = 32; m >= 1; m >>= 1) s += __shfl_xor(s, m);
    __shared__ float r[4];
    int wave = tid >> 6, lane = tid & 63;
    if (lane == 0) r[wave] = s;
    __syncthreads();
    if (tid == 0) {
        float t = r[0] + r[1] + r[2] + r[3] + bp[0];
        float p = 1.f / (1.f + __expf(-t));
        pg[b]   = p;
        out1[b] = p;
    }
}

// ---------------- mid GEMM (split-K 16): M=64, N=1024, K=2048 ---------------
__global__ __launch_bounds__(256, 4) void k_gemm_mid(const float* __restrict__ dec,
                                                     const float* __restrict__ ctx,
                                                     const float* __restrict__ Wm,
                                                     float* __restrict__ pmid) {
    int nt   = blockIdx.x;             // 0..15  (h-tile of 64)
    int kc   = blockIdx.y;             // 0..15  (K-chunk of 128)
    int wave = threadIdx.x >> 6;
    int lane = threadIdx.x & 63;
    int lr   = lane & 15, lg = lane >> 4;
    int col  = nt * 64 + wave * 16 + lr;          // h index
    const float* xb   = (kc < 8) ? dec : ctx;
    int kbase         = (kc & 7) * 128;
    const float* wrow = Wm + (size_t)col * K2 + kc * 128 + lg * 8;
    const float* xrow = xb + (size_t)lr * H_ + kbase + lg * 8;

    f32x4 w0s[4], w1s[4];
#pragma unroll
    for (int p = 0; p < 4; ++p) {
        w0s[p] = *(const f32x4*)(wrow + p * 32);
        w1s[p] = *(const f32x4*)(wrow + p * 32 + 4);
    }
    f32x4 acc[4] = {};
#pragma unroll
    for (int i = 0; i < 4; ++i) {
        f32x4 a0[4], a1[4];
#pragma unroll
        for (int mf = 0; mf < 4; ++mf) {
            const float* xp = xrow + (size_t)(mf * 16) * H_ + i * 32;
            a0[mf] = *(const f32x4*)xp;
            a1[mf] = *(const f32x4*)(xp + 4);
        }
        bf16x8 bf = pack_bf16(w0s[i], w1s[i]);
#pragma unroll
        for (int mf = 0; mf < 4; ++mf) {
            bf16x8 af = pack_bf16(a0[mf], a1[mf]);
            acc[mf] = __builtin_amdgcn_mfma_f32_16x16x32_bf16(af, bf, acc[mf], 0, 0, 0);
        }
    }
#pragma unroll
    for (int mf = 0; mf < 4; ++mf)
#pragma unroll
        for (int r = 0; r < 4; ++r) {
            int row = mf * 16 + lg * 4 + r;       // batch index
            pmid[((size_t)kc * B_ + row) * H_ + col] = acc[mf][r];
        }
}

// ---------------- reduce split-K partials, bias, tanh, -> bf16 --------------
__global__ __launch_bounds__(256) void k_mid_reduce(const float* __restrict__ pmid,
                                                    const float* __restrict__ bm,
                                                    __bf16* __restrict__ midb) {
    int idx = blockIdx.x * 256 + threadIdx.x;     // 65536
    int h = idx & (H_ - 1);
    int m = idx >> 10;
    float s = bm[h];
#pragma unroll
    for (int kc = 0; kc < KCH; ++kc) s += pmid[((size_t)kc * B_ + m) * H_ + h];
    midb[idx] = (__bf16)tanhf(s);
}

// ---------------- big GEMM: e = exp(clip(mid @ Wv^T + bv) - 50) -------------
// Per-wave-private LDS DMA pipeline, NO barriers in the K-loop:
//  * each wave owns 16 vocab rows; stages only those into its 16KB slab
//    (depth-2, K-chunk=128 -> 8KB chunk, 512B contiguous per row).
//  * counted vmcnt(8): chunk c+1's 8 DMAs stay in flight while computing c.
//  * A fragments: 64 VGPRs via asm GLD, issued one chunk ahead, placed in the
//    FIFO before the next W-stage so vmcnt(8) retires them with W(c).
//  * 16B granules XOR-swizzled (t = s ^ (row&15)) at source + read (rule #21).
__global__ __launch_bounds__(256, 2) void k_gemm_vocab(const __bf16* __restrict__ midb,
                                                       const float* __restrict__ Wv,
                                                       const float* __restrict__ bv,
                                                       float* __restrict__ e,
                                                       float* __restrict__ psum) {
    __shared__ __align__(16) char ldsW[65536];    // 4 waves x [2 bufs][16 rows][512]

    int tid  = threadIdx.x;
    int wave = tid >> 6;
    int lane = tid & 63;
    int lr   = lane & 15, lg = lane >> 4;
    int blk  = blockIdx.x;
    int col  = blk * 64 + wave * 16 + lr;         // global vocab col (= Wv row)
    bool valid = col < V_;

    // ---- W DMA source pointers: instr j covers rows wave*16+2j, +2j+1 ------
    const char* Pw[8];
    {
        int h2 = lane >> 5;                       // which row of the pair
        int sl = lane & 31;                       // 16B slot within 512B
#pragma unroll
        for (int j = 0; j < 8; ++j) {
            int r = wave * 16 + 2 * j + h2;       // block-local row
            int grow = blk * 64 + r;
            if (grow >= V_) grow = V_ - 1;
            int t = sl ^ (r & 15);                // source granule (swizzled)
            Pw[j] = (const char*)Wv + (size_t)grow * 4096 + t * 16;
        }
    }
    int wbase = wave * 16384;                     // this wave's slab

    // ---- A sources (midb rows lr+16*mf, k-window lg*8) ----
    const char* bA0 = (const char*)midb + (size_t)lr * 2048 + lg * 16;
    const char* bA1 = bA0 + 16 * 2048;
    const char* bA2 = bA0 + 32 * 2048;
    const char* bA3 = bA0 + 48 * 2048;

    // ---- LDS read offsets: i = ks*2+h -> row lr, granule (ks*8+lg*2+h)^lr --
    int ro[8];
#pragma unroll
    for (int i = 0; i < 8; ++i) {
        int ks = i >> 1, h = i & 1;
        ro[i] = wbase + lr * 512 + (((ks * 8 + lg * 2 + h) ^ lr) << 4);
    }

    bf16x8 af[4][4];                              // [ks][mf], static idx only
    f32x4  acc[4] = {};

#define STAGE(c) do {                                                           \
        _Pragma("unroll")                                                       \
        for (int j = 0; j < 8; ++j)                                             \
            __builtin_amdgcn_global_load_lds((gas_t*)(Pw[j] + (c) * 512),       \
                (las_t*)&ldsW[wbase + (((c) & 1) * 8192) + j * 1024], 16, 0, 0);\
    } while (0)

#define ALOAD(c) do {                                                           \
        GLD(af[0][0], bA0, (c)*256);     GLD(af[0][1], bA1, (c)*256);           \
        GLD(af[0][2], bA2, (c)*256);     GLD(af[0][3], bA3, (c)*256);           \
        GLD(af[1][0], bA0, (c)*256+64);  GLD(af[1][1], bA1, (c)*256+64);        \
        GLD(af[1][2], bA2, (c)*256+64);  GLD(af[1][3], bA3, (c)*256+64);        \
        GLD(af[2][0], bA0, (c)*256+128); GLD(af[2][1], bA1, (c)*256+128);       \
        GLD(af[2][2], bA2, (c)*256+128); GLD(af[2][3], bA3, (c)*256+128);       \
        GLD(af[3][0], bA0, (c)*256+192); GLD(af[3][1], bA1, (c)*256+192);       \
        GLD(af[3][2], bA2, (c)*256+192); GLD(af[3][3], bA3, (c)*256+192);       \
    } while (0)

#define KSTEP(c, ks) do {                                                       \
        f32x4 w0 = *(const f32x4*)&ldsW[ro[2*(ks)]   + (((c) & 1) * 8192)];     \
        f32x4 w1 = *(const f32x4*)&ldsW[ro[2*(ks)+1] + (((c) & 1) * 8192)];     \
        bf16x8 bfr = pack_bf16(w0, w1);                                         \
        acc[0] = __builtin_amdgcn_mfma_f32_16x16x32_bf16(af[ks][0], bfr, acc[0], 0, 0, 0); \
        acc[1] = __builtin_amdgcn_mfma_f32_16x16x32_bf16(af[ks][1], bfr, acc[1], 0, 0, 0); \
        acc[2] = __builtin_amdgcn_mfma_f32_16x16x32_bf16(af[ks][2], bfr, acc[2], 0, 0, 0); \
        acc[3] = __builtin_amdgcn_mfma_f32_16x16x32_bf16(af[ks][3], bfr, acc[3], 0, 0, 0); \
    } while (0)

#define CHUNK(c, N, DOA, DOW) do {                                              \
        asm volatile("s_waitcnt vmcnt(" #N ")" ::: "memory");                   \
        __builtin_amdgcn_sched_barrier(0);                                      \
        KSTEP(c, 0); KSTEP(c, 1); KSTEP(c, 2); KSTEP(c, 3);                     \
        __builtin_amdgcn_sched_barrier(0);                                      \
        if (DOA) ALOAD((c) + 1);                                                \
        if (DOW) STAGE((c) + 2);                                                \
    } while (0)

    // prologue: W0, A0, W1 (FIFO order matters for the counted waits)
    STAGE(0);
    ALOAD(0);
    STAGE(1);

    CHUNK(0, 8, 1, 1); CHUNK(1, 8, 1, 1); CHUNK(2, 8, 1, 1); CHUNK(3, 8, 1, 1);
    CHUNK(4, 8, 1, 1); CHUNK(5, 8, 1, 1); CHUNK(6, 8, 1, 0); CHUNK(7, 0, 0, 0);
#undef CHUNK
#undef KSTEP
#undef ALOAD
#undef STAGE

    // ---- epilogue: per-wave partial sums, no cross-wave LDS ----
    float bias = valid ? bv[col] : 0.f;
#pragma unroll
    for (int mf = 0; mf < 4; ++mf) {
#pragma unroll
        for (int r = 0; r < 4; ++r) {
            int row = mf * 16 + lg * 4 + r;       // batch index
            float logit = acc[mf][r] + bias;
            logit = fminf(fmaxf(logit, -50.f), 50.f);
            float ev = valid ? __expf(logit - 50.f) : 0.f;
            if (valid) e[(size_t)row * VP + col] = ev;
            float s = ev;
            s += __shfl_xor(s, 1); s += __shfl_xor(s, 2);
            s += __shfl_xor(s, 4); s += __shfl_xor(s, 8);
            if (lr == 0) psum[(size_t)row * PSTR + blk * 4 + wave] = s;
        }
    }
}

// ---------------- Z reduction: zinv[b] = 1 / sum psum ----------------------
__global__ __launch_bounds__(256) void k_zred(const float* __restrict__ psum,
                                              float* __restrict__ zinv) {
    int b = blockIdx.x;
    int tid = threadIdx.x;
    float s = 0.f;
    for (int i = tid; i < NB4; i += 256) s += psum[(size_t)b * PSTR + i];
#pragma unroll
    for (int m = 32; m >= 1; m >>= 1) s += __shfl_xor(s, m);
    __shared__ float r[4];
    int wave = tid >> 6, lane = tid & 63;
    if (lane == 0) r[wave] = s;
    __syncthreads();
    if (tid == 0) zinv[b] = 1.f / (r[0] + r[1] + r[2] + r[3]);
}

// ---------------- vocab_dist + generation part of final_dist ---------------
__global__ __launch_bounds__(256) void k_final(const float* __restrict__ e,
                                               const float* __restrict__ zinv,
                                               const float* __restrict__ pg,
                                               float* __restrict__ out0,
                                               float* __restrict__ out2) {
    int idx = blockIdx.x * 256 + threadIdx.x;     // < 64*50100
    if (idx >= B_ * EXTV) return;
    int b = idx / EXTV;
    int v = idx - b * EXTV;
    float o = 0.f;
    if (v < V_) {
        float vd = e[(size_t)b * VP + v] * zinv[b];
        out2[(size_t)b * V_ + v] = vd;
        o = pg[b] * vd;
    }
    out0[idx] = o;
}

// ---------------- copy-distribution scatter --------------------------------
__global__ __launch_bounds__(256) void k_scatter(const float* __restrict__ attn,
                                                 const int* __restrict__ sid,
                                                 const int* __restrict__ oov,
                                                 const float* __restrict__ pg,
                                                 float* __restrict__ out0) {
    int idx = blockIdx.x * 256 + threadIdx.x;
    if (idx >= B_ * S_) return;
    int b = idx / S_;
    int m = oov[idx];
    int tgt = (m >= 0) ? (V_ + m) : sid[idx];
    float w = (1.f - pg[b]) * attn[idx];
    atomicAdd(out0 + (size_t)b * EXTV + tgt, w);
}

extern "C" void kernel_launch(void* const* d_in, const int* in_sizes, int n_in,
                              void* d_out, int out_size, void* d_ws, size_t ws_size,
                              hipStream_t stream) {
    const float* dec  = (const float*)d_in[0];
    const float* ctx  = (const float*)d_in[1];
    const float* emb  = (const float*)d_in[2];
    const float* attn = (const float*)d_in[3];
    const int*   sid  = (const int*)d_in[4];
    const int*   oov  = (const int*)d_in[5];
    // d_in[6] = vocab_size (known statically = 50000)
    const float* Wm   = (const float*)d_in[7];
    const float* bm   = (const float*)d_in[8];
    const float* Wp   = (const float*)d_in[9];
    const float* bp   = (const float*)d_in[10];
    const float* Wv   = (const float*)d_in[11];
    const float* bv   = (const float*)d_in[12];

    float* out0 = (float*)d_out;                  // final_dist [64][50100]
    float* out1 = out0 + (size_t)B_ * EXTV;       // p_gen      [64]
    float* out2 = out1 + B_;                      // vocab_dist [64][50000]

    float*  e    = (float*)d_ws;                  // [64][VP]
    float*  psum = e + (size_t)B_ * VP;           // [64][PSTR]
    float*  zinv = psum + (size_t)B_ * PSTR;      // [64]
    float*  pg   = zinv + 64;                     // [64]
    float*  pmid = pg + 64;                       // [KCH][64][1024]
    __bf16* midb = (__bf16*)(pmid + (size_t)KCH * B_ * H_); // [64][1024]

    k_pgen<<<B_, 256, 0, stream>>>(dec, ctx, emb, Wp, bp, pg, out1);
    dim3 gmid(16, KCH);
    k_gemm_mid<<<gmid, 256, 0, stream>>>(dec, ctx, Wm, pmid);
    k_mid_reduce<<<(B_ * H_) / 256, 256, 0, stream>>>(pmid, bm, midb);
    k_gemm_vocab<<<NBLK, 256, 0, stream>>>((const __bf16*)midb, Wv, bv, e, psum);
    k_zred<<<B_, 256, 0, stream>>>(psum, zinv);
    k_final<<<(B_ * EXTV + 255) / 256, 256, 0, stream>>>(e, zinv, pg, out0, out2);
    k_scatter<<<(B_ * S_ + 255) / 256, 256, 0, stream>>>(attn, sid, oov, pg, out0);
}